// Round 3
// baseline (275.518 us; speedup 1.0000x reference)
//
#include <hip/hip_runtime.h>
#include <hip/hip_bf16.h>

#define NBR   8
#define DV    256    // VOCAB
#define FF    1024   // FFN
#define ROWS  128    // rows per block
#define NCHUNK 16    // FFN chunks of 64

// LDS layout (bytes): B1 dbuf 2x32K | B2 dbuf 2x32K | Hs dbuf 2x16K = 160 KiB
#define L_B1 0
#define L_B2 65536
#define L_HS 131072
#define LDS_BYTES 163840

using bf16x8 = __attribute__((ext_vector_type(8))) short;
using f32x4  = __attribute__((ext_vector_type(4))) float;

__device__ __forceinline__ unsigned short f2bf(float f) {
    unsigned int u = __builtin_bit_cast(unsigned int, f);
    unsigned int r = (u + 0x7fffu + ((u >> 16) & 1u)) >> 16;
    return (unsigned short)r;
}
__device__ __forceinline__ float bf2f(unsigned short h) {
    unsigned int u = ((unsigned int)h) << 16;
    return __builtin_bit_cast(float, u);
}
// gelu(x) ~= x * sigmoid(1.595769122x + 0.0713548163x^3), exp2 domain
__device__ __forceinline__ float gelu_fast(float x) {
    float x2 = x * x;
    float z  = x * fmaf(x2, -0.1029434959f, -2.3022078770f);
    float e  = __builtin_amdgcn_exp2f(z);
    return x * __builtin_amdgcn_rcpf(1.0f + e);
}

#define GLL(gsrc, ldst) __builtin_amdgcn_global_load_lds((const unsigned int*)(gsrc), (unsigned int*)(ldst), 16, 0, 0)
#define MFMA16 __builtin_amdgcn_mfma_f32_16x16x32_bf16

// ---------------- prep: fp32 weights -> bf16 swizzled LDS chunk images ----------------
__global__ void prep_weights(const float* __restrict__ U1, const float* __restrict__ U2,
                             unsigned short* __restrict__ w1img, unsigned short* __restrict__ w2img)
{
    const int b = blockIdx.x;          // 0..127 : n*16 + c
    const int n = b >> 4, cch = b & 15;
    const int tid = threadIdx.x;       // 0..255
    char* img1 = (char*)(w1img) + ((size_t)b << 15);
    char* img2 = (char*)(w2img) + ((size_t)b << 15);
    const float* U1n = U1 + (size_t)n * DV * FF;
    const float* U2n = U2 + (size_t)n * FF * DV;
    #pragma unroll 4
    for (int e = 0; e < 64; ++e) {
        int kk = e * 4 + (tid >> 6);
        int nn = tid & 63;
        float v = U1n[(size_t)kk * FF + cch * 64 + nn];
        unsigned off = ((unsigned)(nn * 256 + kk) * 2u) ^ (unsigned)((nn & 7) << 4);
        *(unsigned short*)(img1 + off) = f2bf(v);
    }
    #pragma unroll 4
    for (int e = 0; e < 64; ++e) {
        int nn = tid;  // 0..255
        float v = U2n[(size_t)(cch * 64 + e) * DV + nn];
        unsigned off = ((unsigned)(nn * 64 + e) * 2u) ^ (unsigned)((nn & 7) << 4);
        *(unsigned short*)(img2 + off) = f2bf(v);
    }
}

// ---------------- main fused kernel: counted-vmcnt 2-phase pipeline ----------------
__global__ __launch_bounds__(512, 2)
void belayer_main(const float* __restrict__ x,
                  const unsigned short* __restrict__ w1img,
                  const unsigned short* __restrict__ w2img,
                  const float* __restrict__ b1g, const float* __restrict__ b2g,
                  const float* __restrict__ lnw, const float* __restrict__ lnb,
                  float* __restrict__ out)
{
    __shared__ __align__(16) char LDS[LDS_BYTES];
    const int tid  = threadIdx.x;
    const int lane = tid & 63;
    const int wave = tid >> 6;          // 0..7
    const int q = lane >> 4, c = lane & 15;
    const int n    = blockIdx.x & 7;    // branch == XCD affinity
    const int tile = blockIdx.x >> 3;
    const int row0 = tile * ROWS;
    const int rowgrp = wave >> 1, colsel = wave & 1;   // GEMM1: 32 rows x 32 ffn
    const int rowg2  = wave >> 2, colg2  = wave & 3;   // GEMM2: 64 rows x 64 cols
    const unsigned swz = (unsigned)((c & 7) << 4);

    const char* g1base = (const char*)w1img + ((size_t)(n * 16) << 15) + (wave << 12) + lane * 16;
    const char* g2base = (const char*)w2img + ((size_t)(n * 16) << 15) + (wave << 12) + lane * 16;

    // prologue DMA: b1[0] -> B1[0], b2[0] -> B2[0]
    #pragma unroll
    for (int i = 0; i < 4; ++i) GLL(g1base + (i << 10), LDS + L_B1 + (wave << 12) + (i << 10));
    #pragma unroll
    for (int i = 0; i < 4; ++i) GLL(g2base + (i << 10), LDS + L_B2 + (wave << 12) + (i << 10));

    // ---- GEMM1 A-frags straight from global x (held resident: 64 VGPR) ----
    bf16x8 A[2][8];
    #pragma unroll
    for (int rf = 0; rf < 2; ++rf) {
        const float* src = x + (((size_t)(row0 + rowgrp * 32 + rf * 16 + c)) * NBR + n) * DV + q * 8;
        #pragma unroll
        for (int ks = 0; ks < 8; ++ks) {
            f32x4 v0 = *(const f32x4*)(src + ks * 32);
            f32x4 v1 = *(const f32x4*)(src + ks * 32 + 4);
            bf16x8 h;
            h[0] = (short)f2bf(v0[0]); h[1] = (short)f2bf(v0[1]);
            h[2] = (short)f2bf(v0[2]); h[3] = (short)f2bf(v0[3]);
            h[4] = (short)f2bf(v1[0]); h[5] = (short)f2bf(v1[1]);
            h[6] = (short)f2bf(v1[2]); h[7] = (short)f2bf(v1[3]);
            A[rf][ks] = h;
        }
    }

    // ---- precomputed swizzled LDS addresses (dual even/odd-k bases) ----
    const unsigned nn01 = (unsigned)(colsel * 32 + c);
    const unsigned aB1e = (nn01 * 512 + q * 16) ^ swz;
    const unsigned aB1o = (nn01 * 512 + q * 16 + 64) ^ swz;
    const unsigned rr0  = (unsigned)(rowg2 * 64 + c);
    const unsigned aHe  = (rr0 * 128 + q * 16) ^ swz;
    const unsigned aHo  = (rr0 * 128 + q * 16 + 64) ^ swz;
    const unsigned nn02 = (unsigned)(colg2 * 64 + c);
    const unsigned aB2e = (nn02 * 128 + q * 16) ^ swz;
    const unsigned aB2o = (nn02 * 128 + q * 16 + 64) ^ swz;
    unsigned aW[4][2];
    #pragma unroll
    for (int r = 0; r < 4; ++r)
        #pragma unroll
        for (int cf = 0; cf < 2; ++cf)
            aW[r][cf] = (unsigned)(((rowgrp * 32 + q * 4 + r) * 128 + (colsel * 32 + cf * 16 + c) * 2)
                                   ^ ((((q & 1) * 4 + r)) << 4));

    f32x4 acc2[4][4];
    #pragma unroll
    for (int i = 0; i < 4; ++i)
        #pragma unroll
        for (int j = 0; j < 4; ++j) acc2[i][j] = (f32x4){0.f, 0.f, 0.f, 0.f};

    asm volatile("s_waitcnt vmcnt(0)" ::: "memory");
    __builtin_amdgcn_s_barrier();
    asm volatile("" ::: "memory");

#define G2_PHASE(TPREV)                                                                     \
    {                                                                                       \
        const unsigned hOff  = L_HS + ((((TPREV) & 1)) << 14);                              \
        const unsigned b2Off = L_B2 + ((((TPREV) & 1)) << 15);                              \
        _Pragma("unroll")                                                                   \
        for (int ks = 0; ks < 2; ++ks) {                                                    \
            const unsigned hb = (ks ? aHo : aHe) + hOff;                                    \
            const unsigned bb = (ks ? aB2o : aB2e) + b2Off;                                 \
            bf16x8 af[4], bfr[4];                                                           \
            _Pragma("unroll")                                                               \
            for (int rf = 0; rf < 4; ++rf) af[rf]  = *(const bf16x8*)(LDS + hb + rf * 2048);\
            _Pragma("unroll")                                                               \
            for (int cf = 0; cf < 4; ++cf) bfr[cf] = *(const bf16x8*)(LDS + bb + cf * 2048);\
            _Pragma("unroll")                                                               \
            for (int rf = 0; rf < 4; ++rf)                                                  \
                _Pragma("unroll")                                                           \
                for (int cf = 0; cf < 4; ++cf)                                              \
                    acc2[rf][cf] = MFMA16(af[rf], bfr[cf], acc2[rf][cf], 0, 0, 0);          \
        }                                                                                   \
    }

    #pragma unroll 2
    for (int t = 0; t < NCHUNK; ++t) {
        const int tsrc = (t < NCHUNK - 1) ? (t + 1) : (NCHUNK - 1);  // clamp: dummy reload of last image
        // ---------------- phase A: GLL b1[t+1] || GEMM2[t-1] ----------------
        {
            const char* g = g1base + ((size_t)tsrc << 15);
            char* l = LDS + L_B1 + (((t + 1) & 1) << 15) + (wave << 12);
            #pragma unroll
            for (int i = 0; i < 4; ++i) GLL(g + (i << 10), l + (i << 10));
        }
        if (t >= 1) G2_PHASE(t - 1)
        asm volatile("s_waitcnt vmcnt(8)\n\ts_waitcnt lgkmcnt(0)" ::: "memory");
        __builtin_amdgcn_s_barrier();
        asm volatile("" ::: "memory");
        // ---------------- phase B: GLL b2[t+1] || GEMM1[t] -> Hs[t&1] ----------------
        {
            const char* g = g2base + ((size_t)tsrc << 15);
            char* l = LDS + L_B2 + (((t + 1) & 1) << 15) + (wave << 12);
            #pragma unroll
            for (int i = 0; i < 4; ++i) GLL(g + (i << 10), l + (i << 10));
        }
        {
            const unsigned b1Off = L_B1 + ((t & 1) << 15);
            f32x4 acc1[2][2];
            #pragma unroll
            for (int i = 0; i < 2; ++i)
                #pragma unroll
                for (int j = 0; j < 2; ++j) acc1[i][j] = (f32x4){0.f, 0.f, 0.f, 0.f};
            #pragma unroll
            for (int ks = 0; ks < 8; ++ks) {
                const unsigned bb = ((ks & 1) ? aB1o : aB1e) + b1Off + (ks >> 1) * 128;
                bf16x8 b0 = *(const bf16x8*)(LDS + bb);
                bf16x8 b1 = *(const bf16x8*)(LDS + bb + 8192);
                acc1[0][0] = MFMA16(A[0][ks], b0, acc1[0][0], 0, 0, 0);
                acc1[0][1] = MFMA16(A[0][ks], b1, acc1[0][1], 0, 0, 0);
                acc1[1][0] = MFMA16(A[1][ks], b0, acc1[1][0], 0, 0, 0);
                acc1[1][1] = MFMA16(A[1][ks], b1, acc1[1][1], 0, 0, 0);
            }
            const unsigned hw = L_HS + ((t & 1) << 14);
            #pragma unroll
            for (int cf = 0; cf < 2; ++cf) {
                float b1v = b1g[n * FF + t * 64 + colsel * 32 + cf * 16 + c];
                #pragma unroll
                for (int rf = 0; rf < 2; ++rf)
                    #pragma unroll
                    for (int r = 0; r < 4; ++r) {
                        float g = gelu_fast(acc1[rf][cf][r] + b1v);
                        *(unsigned short*)(LDS + hw + aW[r][cf] + rf * 2048) = f2bf(g);
                    }
            }
        }
        asm volatile("s_waitcnt vmcnt(8)\n\ts_waitcnt lgkmcnt(0)" ::: "memory");
        __builtin_amdgcn_s_barrier();
        asm volatile("" ::: "memory");
    }
    // tail: GEMM2 for chunk 15 (Hs[1], B2[1]; b2[15] drained by last vmcnt(8))
    G2_PHASE(NCHUNK - 1)

    // ---- epilogue: skip loads (early), +b2, cross-wave LN(256), gelu, +skip, store ----
    float skp[4][4][4];
    #pragma unroll
    for (int rf = 0; rf < 4; ++rf)
        #pragma unroll
        for (int r = 0; r < 4; ++r) {
            const float* xr = x + ((size_t)(row0 + rowg2 * 64 + rf * 16 + q * 4 + r) * NBR + n) * DV;
            #pragma unroll
            for (int cf = 0; cf < 4; ++cf)
                skp[rf][cf][r] = xr[colg2 * 64 + cf * 16 + c];
        }
    float b2v[4];
    #pragma unroll
    for (int cf = 0; cf < 4; ++cf) b2v[cf] = b2g[n * DV + colg2 * 64 + cf * 16 + c];

    float sA[4][4], sQ[4][4];
    #pragma unroll
    for (int rf = 0; rf < 4; ++rf)
        #pragma unroll
        for (int r = 0; r < 4; ++r) { sA[rf][r] = 0.f; sQ[rf][r] = 0.f; }
    #pragma unroll
    for (int rf = 0; rf < 4; ++rf)
        #pragma unroll
        for (int cf = 0; cf < 4; ++cf)
            #pragma unroll
            for (int r = 0; r < 4; ++r) {
                float v = acc2[rf][cf][r] + b2v[cf];
                acc2[rf][cf][r] = v;
                sA[rf][r] += v;
                sQ[rf][r] += v * v;
            }
    #pragma unroll
    for (int m = 1; m < 16; m <<= 1)
        #pragma unroll
        for (int rf = 0; rf < 4; ++rf)
            #pragma unroll
            for (int r = 0; r < 4; ++r) {
                sA[rf][r] += __shfl_xor(sA[rf][r], m, 64);
                sQ[rf][r] += __shfl_xor(sQ[rf][r], m, 64);
            }
    // partials -> LDS (reuse Hs buf0: disjoint from Hs buf1 read by tail G2)
    float* Lred = (float*)(LDS + L_HS);
    if (c == 0) {
        #pragma unroll
        for (int rf = 0; rf < 4; ++rf)
            #pragma unroll
            for (int r = 0; r < 4; ++r) {
                int row = rowg2 * 64 + rf * 16 + q * 4 + r;
                Lred[colg2 * 128 + row]       = sA[rf][r];
                Lred[512 + colg2 * 128 + row] = sQ[rf][r];
            }
    }
    __syncthreads();
    float mu[4][4], rs[4][4];
    #pragma unroll
    for (int rf = 0; rf < 4; ++rf)
        #pragma unroll
        for (int r = 0; r < 4; ++r) {
            int row = rowg2 * 64 + rf * 16 + q * 4 + r;
            float ssum = Lred[row] + Lred[128 + row] + Lred[256 + row] + Lred[384 + row];
            float qsum = Lred[512 + row] + Lred[640 + row] + Lred[768 + row] + Lred[896 + row];
            float m_ = ssum * (1.0f / 256.0f);
            float var = qsum * (1.0f / 256.0f) - m_ * m_;
            mu[rf][r] = m_;
            rs[rf][r] = rsqrtf(var + 1e-5f);
        }
    #pragma unroll
    for (int cf = 0; cf < 4; ++cf) {
        int col = colg2 * 64 + cf * 16 + c;
        float lw = lnw[col];
        float lb = lnb[col];
        #pragma unroll
        for (int rf = 0; rf < 4; ++rf)
            #pragma unroll
            for (int r = 0; r < 4; ++r) {
                int row = rowg2 * 64 + rf * 16 + q * 4 + r;
                float v = (acc2[rf][cf][r] - mu[rf][r]) * rs[rf][r] * lw + lb;
                float g = gelu_fast(v);
                out[((size_t)(row0 + row) * NBR + n) * DV + col] = skp[rf][cf][r] + g;
            }
    }
#undef G2_PHASE
}

extern "C" void kernel_launch(void* const* d_in, const int* in_sizes, int n_in,
                              void* d_out, int out_size, void* d_ws, size_t ws_size,
                              hipStream_t stream) {
    const float* x   = (const float*)d_in[0];
    const float* U1  = (const float*)d_in[1];
    const float* b1  = (const float*)d_in[2];
    const float* U2  = (const float*)d_in[3];
    const float* b2  = (const float*)d_in[4];
    const float* lnw = (const float*)d_in[5];
    const float* lnb = (const float*)d_in[6];
    float* out = (float*)d_out;

    unsigned short* w1img = (unsigned short*)d_ws;               // 4 MB
    unsigned short* w2img = w1img + (size_t)4 * 1024 * 1024 / 2; // 4 MB

    prep_weights<<<dim3(128), dim3(256), 0, stream>>>(U1, U2, w1img, w2img);
    belayer_main<<<dim3(1024), dim3(512), 0, stream>>>(x, w1img, w2img, b1, b2, lnw, lnb, out);
}